// Round 9
// baseline (1641.718 us; speedup 1.0000x reference)
//
#include <hip/hip_runtime.h>
#include <math.h>

#define BB 4
#define TT 4
#define CC 256
#define HH 30
#define WW 40
#define HWS (HH*WW)          // 1200
#define CHW (CC*HWS)         // 307200
#define NCG 32               // ci-groups of 8
#define PXS (NCG*HWS*8)      // f16 elements per blocked image [32][1200][8]
#define PL 168               // LDS plane stride in pixels

typedef __attribute__((ext_vector_type(8))) _Float16 half8;
typedef __attribute__((ext_vector_type(4))) float f32x4;

// ---------------------------------------------------------------------------
// Pack x (all B,T) to f16 blocked pixel-major: x16[b][t][cig][p][8]
// ---------------------------------------------------------------------------
__global__ void pack_x16(const float* __restrict__ x, _Float16* __restrict__ x16) {
    int id = blockIdx.x * 256 + threadIdx.x;
    if (id >= BB * TT * NCG * HWS) return;
    int p = id % HWS;
    int cig = (id / HWS) % NCG;
    int bt = id / (HWS * NCG);
    const float* src = x + ((size_t)bt * CC + cig * 8) * HWS + p;
    half8 hv;
#pragma unroll
    for (int j = 0; j < 8; ++j) hv[j] = (_Float16)src[(size_t)j * HWS];
    *(half8*)&x16[(size_t)id * 8] = hv;
}

// ---------------------------------------------------------------------------
// h0 = sum_t x; c0 = h0.  c stays f32 [B][C][HW]; h emitted f16 blocked.
// ---------------------------------------------------------------------------
__global__ void init_hc(const float* __restrict__ x, _Float16* __restrict__ h16,
                        float* __restrict__ c) {
    int id = blockIdx.x * 256 + threadIdx.x;
    if (id >= BB * NCG * HWS) return;
    int p = id % HWS;
    int cig = (id / HWS) % NCG;
    int b = id / (HWS * NCG);
    float s[8];
#pragma unroll
    for (int j = 0; j < 8; ++j) s[j] = 0.f;
#pragma unroll
    for (int t = 0; t < TT; ++t) {
        const float* src = x + (((size_t)b * TT + t) * CC + cig * 8) * HWS + p;
#pragma unroll
        for (int j = 0; j < 8; ++j) s[j] += src[(size_t)j * HWS];
    }
    half8 hv;
    float* cp = c + ((size_t)b * CC + cig * 8) * HWS + p;
#pragma unroll
    for (int j = 0; j < 8; ++j) { cp[(size_t)j * HWS] = s[j]; hv[j] = (_Float16)s[j]; }
    *(half8*)&h16[(size_t)id * 8] = hv;
}

// ---------------------------------------------------------------------------
// xtilde16[b][cig][p][8] = (f16)(x_f32[b,t,ci,p] * a[b,p])
// ---------------------------------------------------------------------------
__global__ void xtilde_kernel(const float* __restrict__ xt, const float* __restrict__ a,
                              _Float16* __restrict__ xt16) {
    int id = blockIdx.x * 256 + threadIdx.x;
    if (id >= BB * NCG * HWS) return;
    int p = id % HWS;
    int cig = (id / HWS) % NCG;
    int b = id / (HWS * NCG);
    float sc = a[(size_t)b * HWS + p];
    const float* src = xt + ((size_t)b * TT * CC + cig * 8) * HWS + p;
    half8 hv;
#pragma unroll
    for (int j = 0; j < 8; ++j) hv[j] = (_Float16)(src[(size_t)j * HWS] * sc);
    *(half8*)&xt16[(size_t)id * 8] = hv;
}

// ---------------------------------------------------------------------------
// Pack weights to f16: layout [kg=k/8][Cout][k%8]
// ---------------------------------------------------------------------------
__global__ void pack_weights(const float* __restrict__ W1,
                             const float* __restrict__ W2,
                             _Float16* __restrict__ wt, int Cout) {
    int idx = blockIdx.x * 256 + threadIdx.x;
    if (idx >= 4608 * Cout) return;
    int k = idx / Cout;
    int n = idx - k * Cout;
    float v = (k < 2304) ? W1[(size_t)k * Cout + n]
                         : W2[(size_t)(k - 2304) * Cout + n];
    wt[((size_t)(k >> 3) * Cout + n) * 8 + (k & 7)] = (_Float16)v;
}

// ---------------------------------------------------------------------------
// MFMA dual 3x3 conv (R4-exact production structure) + ABLATION variants.
// VAR: 0=full, 1=no in-loop staging, 2=no ds_reads (af const; volatile token
// keeps staging alive, rule#17), 3=no in-loop WLOADs (fixed prologue weights).
// REPEAT: outer repetition of the kiter loop (ablation dispatches use 4 so
// they rank in the rocprof top-5; production uses 1). All variants keep the
// MFMA stream -> floor ~83us at REPEAT=4, always above the 51.6us production
// row. Ablation outputs go to dead scratch; checked outputs untouched.
// ---------------------------------------------------------------------------
template<int NW, int NZ, int NY, int ZT, int VAR, int REPEAT>
__global__ __launch_bounds__(256, 2) void conv_mfma(
    const _Float16* __restrict__ in0, long bs0,
    const _Float16* __restrict__ in1, long bs1,
    const _Float16* __restrict__ wt,
    const float* __restrict__ b1, const float* __restrict__ b2,
    float* __restrict__ out, int Cout)
{
    constexpr int NK = 8 / NZ;                      // K-iters (32 ci each)
    constexpr int SLICES = NY * ZT;
    constexpr int PERX = SLICES / 8;                // slices per XCD
    constexpr int MU = 60;                          // M-units per slice
    __shared__ alignas(16) _Float16 s_a[2][4 * PL * 8];

    const int tid = threadIdx.x;
    const int l = tid & 63, wv = tid >> 6;
    const int q = l >> 4, r = l & 15;

    // ---- XCD-homed slice decode ----
    const int lin = blockIdx.x;
    const int xcd = lin & 7;
    const int idx = lin >> 3;
    const int sl = xcd * PERX + idx / MU;
    const int mb = idx % MU;
    const int zz = sl / NY;
    const int yy = sl - zz * NY;

    const int b = mb / 15;
    const int pix0 = (mb % 15) * 80;
    const int y0 = (mb % 15) * 2;
    const int n0 = yy * (4 * NW * 16) + wv * (NW * 16);
    const int src = zz / NZ;
    const int ci_start = (zz % NZ) * (CC / NZ);
    const int kgb0 = src * 288 + (ci_start >> 3);

    const _Float16* inp = src ? (in1 + (size_t)b * bs1) : (in0 + (size_t)b * bs0);

    // ---- per-thread staging geometry (3 items) ----
    bool iv[3], pv[3];
    const _Float16* pj[3];
    int ldsoff[3];
#pragma unroll
    for (int j = 0; j < 3; ++j) {
        int item = tid + j * 256;
        iv[j] = item < 672;
        int it = iv[j] ? item : 0;
        int cig = it / 168;
        int pix = it - cig * 168;
        int row = pix / 42;
        int px = pix - row * 42;
        int xx = px - 1, yy2 = y0 + row - 1;
        pv[j] = iv[j] && xx >= 0 && xx < WW && yy2 >= 0 && yy2 < HH;
        pj[j] = inp + ((size_t)((ci_start >> 3) + cig) * HWS + yy2 * WW + xx) * 8;
        ldsoff[j] = (cig * PL + pix) * 8;
    }

    // ---- accumulators ----
    f32x4 acc[5][NW];
#pragma unroll
    for (int nt = 0; nt < NW; ++nt) {
        int co = n0 + nt * 16 + r;
        float bias = (zz == 0) ? (b1[co] + b2[co]) : 0.f;
        f32x4 bv = {bias, bias, bias, bias};
#pragma unroll
        for (int mt = 0; mt < 5; ++mt) acc[mt][nt] = bv;
    }

    // ---- per-mt LDS pixel base ----
    int hbase[5];
#pragma unroll
    for (int m5 = 0; m5 < 5; ++m5) {
        int p = m5 * 16 + r;
        int ry = p / 40;
        int rx = p - ry * 40;
        hbase[m5] = ry * 42 + rx;
    }

    // ---- staging: pure b128 copy ----
    half8 sr[3];
    auto stage_issue = [&](int kk) {
#pragma unroll
        for (int j = 0; j < 3; ++j) if (pv[j])
            sr[j] = *(const half8*)(pj[j] + (size_t)kk * (4 * HWS * 8));
    };
    auto stage_write = [&](int kk) {
#pragma unroll
        for (int j = 0; j < 3; ++j) if (iv[j]) {
            half8 hv = {0, 0, 0, 0, 0, 0, 0, 0};
            if (pv[j]) hv = sr[j];
            *(half8*)&s_a[kk & 1][ldsoff[j]] = hv;
        }
    };

    const half8* wp = (const half8*)wt;
    half8 w0[NW], w1[NW], w2[NW], w3[NW];

    // VAR2: constant A-fragment (removes ds_reads; MFMA cost value-independent)
    half8 cst;
#pragma unroll
    for (int j = 0; j < 8; ++j) cst[j] = (_Float16)0.5f;

#define WLOAD_RAW(SLOT, TAP) do {                                          \
    const int kg_ = kgb0 + k * 4 + (TAP) * 32 + q;                         \
    _Pragma("unroll")                                                      \
    for (int nt = 0; nt < NW; ++nt)                                        \
        SLOT[nt] = wp[(size_t)kg_ * Cout + n0 + nt * 16 + r];              \
} while (0)

#define WLOADC(SLOT, TAP) do {                                             \
    if constexpr (VAR != 3) WLOAD_RAW(SLOT, TAP);                          \
} while (0)

#define CTAP(SLOT, TAP) do {                                               \
    constexpr int dy_ = (TAP) / 3, dx_ = (TAP) % 3;                        \
    _Pragma("unroll")                                                      \
    for (int mt = 0; mt < 5; ++mt) {                                       \
        half8 af;                                                          \
        if constexpr (VAR == 2) af = cst;                                  \
        else af = *(const half8*)&s_a[k & 1]                               \
            [(q * PL + hbase[mt] + dy_ * 42 + dx_) * 8];                   \
        _Pragma("unroll")                                                  \
        for (int nt = 0; nt < NW; ++nt)                                    \
            acc[mt][nt] = __builtin_amdgcn_mfma_f32_16x16x32_f16(          \
                af, SLOT[nt], acc[mt][nt], 0, 0, 0);                       \
    }                                                                      \
} while (0)

    // prologue: stage tile 0
    stage_issue(0);
    stage_write(0);

    // VAR3 prologue: fixed weights in all four rotation slots
    if constexpr (VAR == 3) {
        const int k = 0;
        WLOAD_RAW(w0, 0); WLOAD_RAW(w1, 1); WLOAD_RAW(w2, 2); WLOAD_RAW(w3, 3);
    }

#pragma unroll
    for (int rep = 0; rep < REPEAT; ++rep) {
#pragma unroll
        for (int k = 0; k < NK; ++k) {
            WLOADC(w0, 0); WLOADC(w1, 1); WLOADC(w2, 2);
            if constexpr (VAR != 1) { if (k + 1 < NK) stage_issue(k + 1); }
            __syncthreads();
            if constexpr (VAR == 2) {
                // volatile token read: keeps staging live without the 45
                // per-kiter A-fragment reads (rule #17 DCE guard)
                float tokf = *(const volatile float*)&s_a[k & 1][tid * 2];
                asm volatile("" :: "v"(tokf));
            }
            __builtin_amdgcn_s_setprio(1);
            WLOADC(w3, 3); CTAP(w0, 0);
            WLOADC(w0, 4); CTAP(w1, 1);
            WLOADC(w1, 5); CTAP(w2, 2);
            WLOADC(w2, 6); CTAP(w3, 3);
            WLOADC(w3, 7); CTAP(w0, 4);
            WLOADC(w0, 8); CTAP(w1, 5);
            CTAP(w2, 6);
            CTAP(w3, 7);
            CTAP(w0, 8);
            __builtin_amdgcn_s_setprio(0);
            if constexpr (VAR != 1) { if (k + 1 < NK) stage_write(k + 1); }
        }
    }
#undef WLOAD_RAW
#undef WLOADC
#undef CTAP

    out += (size_t)zz * BB * Cout * HWS;
#pragma unroll
    for (int mt = 0; mt < 5; ++mt) {
#pragma unroll
        for (int nt = 0; nt < NW; ++nt) {
            int co = n0 + nt * 16 + r;
            int p = pix0 + mt * 16 + q * 4;
            *(f32x4*)&out[((size_t)b * Cout + co) * HWS + p] = acc[mt][nt];
        }
    }
}

// ---------------------------------------------------------------------------
// att = tanh(a0 + a1 + a2 + a3)  (4 stacked K-split partials, float4 loads)
// ---------------------------------------------------------------------------
__global__ void add_tanh4(const float* __restrict__ a0,
                          float* __restrict__ o, int n4) {
    int id = blockIdx.x * 256 + threadIdx.x;
    if (id >= n4) return;
    const f32x4* av = (const f32x4*)a0;
    f32x4 s = av[id] + av[id + (size_t)n4] + av[id + 2 * (size_t)n4]
            + av[id + 3 * (size_t)n4];
    f32x4 rr;
#pragma unroll
    for (int j = 0; j < 4; ++j) rr[j] = tanhf(s[j]);
    ((f32x4*)o)[id] = rr;
}

// ---------------------------------------------------------------------------
// K-split attention score
// ---------------------------------------------------------------------------
__global__ __launch_bounds__(256) void att_e_part(
    const float* __restrict__ att, const float* __restrict__ Va,
    float* __restrict__ part)
{
    __shared__ float red[4][64];
    const int lane = threadIdx.x & 63, wv = threadIdx.x >> 6;
    const int p = blockIdx.x * 64 + lane;
    const int b = blockIdx.y, ch = blockIdx.z;
    const bool valid = (p < HWS);
    const int pc = valid ? p : 0;
    const int y = pc / WW, x = pc - (pc / WW) * WW;

    float acc = 0.f;
    if (valid) {
        const int ca0 = ch * 32 + wv * 8;
#pragma unroll
        for (int j = 0; j < 8; ++j) {
            const int ca = ca0 + j;
            const float* base = att + ((size_t)b * CC + ca) * HWS;
            const float* va = Va + ca;
#pragma unroll
            for (int dy = 0; dy < 3; ++dy) {
                int yy = y + dy - 1;
                if (yy < 0 || yy >= HH) continue;
#pragma unroll
                for (int dx = 0; dx < 3; ++dx) {
                    int xx = x + dx - 1;
                    if (xx < 0 || xx >= WW) continue;
                    acc = fmaf(base[yy * WW + xx], va[(dy * 3 + dx) * CC], acc);
                }
            }
        }
    }
    red[wv][lane] = acc;
    __syncthreads();
    if (wv == 0 && valid)
        part[((size_t)b * 8 + ch) * HWS + p] =
            red[0][lane] + red[1][lane] + red[2][lane] + red[3][lane];
}

// ---------------------------------------------------------------------------
// softmax over HW per batch, summing the 8 K-split partials first (in LDS)
// ---------------------------------------------------------------------------
__global__ __launch_bounds__(256) void softmax_kernel(
    const float* __restrict__ part, float* __restrict__ a)
{
    __shared__ float se[HWS];
    __shared__ float red[256];
    int b = blockIdx.x;
    int tid = threadIdx.x;

    for (int i = tid; i < HWS; i += 256) {
        float s = 0.f;
#pragma unroll
        for (int ch = 0; ch < 8; ++ch)
            s += part[((size_t)b * 8 + ch) * HWS + i];
        se[i] = s;
    }
    __syncthreads();

    float m = -1e30f;
    for (int i = tid; i < HWS; i += 256) m = fmaxf(m, se[i]);
    red[tid] = m;
    __syncthreads();
    for (int s = 128; s > 0; s >>= 1) {
        if (tid < s) red[tid] = fmaxf(red[tid], red[tid + s]);
        __syncthreads();
    }
    m = red[0];
    __syncthreads();

    float sum = 0.f;
    for (int i = tid; i < HWS; i += 256) {
        float v = expf(se[i] - m);
        se[i] = v;
        sum += v;
    }
    red[tid] = sum;
    __syncthreads();
    for (int s = 128; s > 0; s >>= 1) {
        if (tid < s) red[tid] += red[tid + s];
        __syncthreads();
    }
    float inv = 1.f / red[0];
    for (int i = tid; i < HWS; i += 256)
        a[(size_t)b * HWS + i] = se[i] * inv;
}

// ---------------------------------------------------------------------------
// LSTM gate update; emits h16 (blocked f16) always, h f32 only on last step.
// ---------------------------------------------------------------------------
__global__ void gate_update(const float* __restrict__ g0, const float* __restrict__ g1,
                            float* __restrict__ c, _Float16* __restrict__ h16,
                            float* __restrict__ h32) {
    int id = blockIdx.x * 256 + threadIdx.x;
    if (id >= BB * NCG * HWS) return;
    int p = id % HWS;
    int cig = (id / HWS) % NCG;
    int b = id / (HWS * NCG);
    const int ci0 = cig * 8;
    half8 hv;
#pragma unroll
    for (int j = 0; j < 8; ++j) {
        size_t base = ((size_t)b * 4 * CC + ci0 + j) * HWS + p;
        float gi = g0[base] + g1[base];
        float gf = g0[base + (size_t)CHW] + g1[base + (size_t)CHW];
        float gc = g0[base + 2 * (size_t)CHW] + g1[base + 2 * (size_t)CHW];
        float go = g0[base + 3 * (size_t)CHW] + g1[base + 3 * (size_t)CHW];
        float i_ = 1.f / (1.f + expf(-gi));
        float f_ = 1.f / (1.f + expf(-gf));
        float o_ = 1.f / (1.f + expf(-go));
        size_t cix = ((size_t)b * CC + ci0 + j) * HWS + p;
        float cn = f_ * c[cix] + i_ * tanhf(gc);
        c[cix] = cn;
        float hn = o_ * tanhf(cn);
        hv[j] = (_Float16)hn;
        if (h32) h32[cix] = hn;
    }
    *(half8*)&h16[(size_t)id * 8] = hv;
}

// ---------------------------------------------------------------------------
extern "C" void kernel_launch(void* const* d_in, const int* in_sizes, int n_in,
                              void* d_out, int out_size, void* d_ws, size_t ws_size,
                              hipStream_t stream) {
    const float* x   = (const float*)d_in[0];
    const float* Wa  = (const float*)d_in[1];
    const float* ba  = (const float*)d_in[2];
    const float* Ua  = (const float*)d_in[3];
    const float* bua = (const float*)d_in[4];
    const float* Va  = (const float*)d_in[5];
    const float* Wx  = (const float*)d_in[6];
    const float* bx  = (const float*)d_in[7];
    const float* Uh  = (const float*)d_in[8];
    const float* bh  = (const float*)d_in[9];
    float* out = (float*)d_out;

    char* wsb = (char*)d_ws;
    const size_t NCHW = (size_t)BB * CHW;
    _Float16* wtg  = (_Float16*)wsb;              wsb += (size_t)4608 * 1024 * 2;
    _Float16* wta  = (_Float16*)wsb;              wsb += (size_t)4608 * 256 * 2;
    _Float16* x16  = (_Float16*)wsb;              wsb += (size_t)BB * TT * PXS * 2;
    _Float16* h16  = (_Float16*)wsb;              wsb += (size_t)BB * PXS * 2;
    _Float16* xt16 = (_Float16*)wsb;              wsb += (size_t)BB * PXS * 2;
    float* cb   = (float*)wsb;                    wsb += NCHW * 4;
    float* g01  = (float*)wsb;                    wsb += 8 * NCHW * 4;   // z-stacked
    float* att  = (float*)wsb;                    wsb += NCHW * 4;
    float* part = (float*)wsb;                    wsb += (size_t)BB * 8 * HWS * 4;
    float* a    = (float*)wsb;
    // att01 (4 z-stacked partials, Cout=256) aliases g01 (disjoint lifetime)
    float* att01 = g01;

    pack_weights<<<dim3((4608 * 1024 + 255) / 256), dim3(256), 0, stream>>>(
        Wx, Uh, wtg, 1024);
    pack_weights<<<dim3((4608 * 256 + 255) / 256), dim3(256), 0, stream>>>(
        Wa, Ua, wta, 256);
    pack_x16<<<dim3((BB * TT * NCG * HWS + 255) / 256), dim3(256), 0, stream>>>(
        x, x16);

    const int nblk = BB * NCG * HWS;              // 153600
    init_hc<<<dim3((nblk + 255) / 256), dim3(256), 0, stream>>>(x, h16, cb);

    const int n4 = (int)(NCHW / 4);

    for (int t = 0; t < TT; ++t) {
        // attention partials: NW=2, 8 slices x 60 M-units = 480 blocks.
        conv_mfma<2, 2, 2, 4, 0, 1><<<dim3(480), dim3(256), 0, stream>>>(
            h16, (long)PXS, x16 + (size_t)t * PXS, (long)TT * PXS,
            wta, ba, bua, att01, 256);
        add_tanh4<<<dim3((n4 + 255) / 256), dim3(256), 0, stream>>>(
            att01, att, n4);

        att_e_part<<<dim3(19, BB, 8), dim3(256), 0, stream>>>(att, Va, part);
        softmax_kernel<<<dim3(BB), dim3(256), 0, stream>>>(part, a);

        xtilde_kernel<<<dim3((nblk + 255) / 256), dim3(256), 0, stream>>>(
            x + (size_t)t * CHW, a, xt16);

        // gates: NW=4, 8 slices x 60 M-units = 480 blocks (R4-exact).
        conv_mfma<4, 1, 4, 2, 0, 1><<<dim3(480), dim3(256), 0, stream>>>(
            xt16, (long)PXS, h16, (long)PXS, wtg, bx, bh, g01, 1024);

        gate_update<<<dim3((nblk + 255) / 256), dim3(256), 0, stream>>>(
            g01, g01 + 4 * NCHW, cb, h16, (t == TT - 1) ? out : nullptr);
    }

    // ======================== DIAGNOSTIC ABLATIONS =========================
    // Run AFTER the final gate_update (g01 is dead -> used as scratch output).
    // REPEAT=4 so each ranks in the rocprof top-5. Within-probe A/B:
    //   VAR0 = scaled full baseline (~4x52 = 208us expected)
    //   VAR1 = no in-loop staging     -> collapse = staging/global-latency wall
    //   VAR2 = no A-fragment ds_reads -> collapse = LDS-read-latency wall
    //   VAR3 = no in-loop weight loads-> collapse = weight-L2-latency wall
    //   none collapse                 -> per-kiter fixed overhead (barrier)
    conv_mfma<4, 1, 4, 2, 0, 4><<<dim3(480), dim3(256), 0, stream>>>(
        xt16, (long)PXS, h16, (long)PXS, wtg, bx, bh, g01, 1024);
    conv_mfma<4, 1, 4, 2, 1, 4><<<dim3(480), dim3(256), 0, stream>>>(
        xt16, (long)PXS, h16, (long)PXS, wtg, bx, bh, g01, 1024);
    conv_mfma<4, 1, 4, 2, 2, 4><<<dim3(480), dim3(256), 0, stream>>>(
        xt16, (long)PXS, h16, (long)PXS, wtg, bx, bh, g01, 1024);
    conv_mfma<4, 1, 4, 2, 3, 4><<<dim3(480), dim3(256), 0, stream>>>(
        xt16, (long)PXS, h16, (long)PXS, wtg, bx, bh, g01, 1024);
}

// Round 11
// 549.981 us; speedup vs baseline: 2.9850x; 2.9850x over previous
//
#include <hip/hip_runtime.h>
#include <math.h>

#define BB 4
#define TT 4
#define CC 256
#define HH 30
#define WW 40
#define HWS (HH*WW)          // 1200
#define CHW (CC*HWS)         // 307200
#define NCG 32               // ci-groups of 8
#define PXS (NCG*HWS*8)      // f16 elements per blocked image [32][1200][8]
#define PL 168               // LDS plane stride in pixels

typedef __attribute__((ext_vector_type(8))) _Float16 half8;
typedef __attribute__((ext_vector_type(4))) float f32x4;

// ---------------------------------------------------------------------------
// Pack x (all B,T) to f16 blocked pixel-major: x16[b][t][cig][p][8]
// ---------------------------------------------------------------------------
__global__ void pack_x16(const float* __restrict__ x, _Float16* __restrict__ x16) {
    int id = blockIdx.x * 256 + threadIdx.x;
    if (id >= BB * TT * NCG * HWS) return;
    int p = id % HWS;
    int cig = (id / HWS) % NCG;
    int bt = id / (HWS * NCG);
    const float* src = x + ((size_t)bt * CC + cig * 8) * HWS + p;
    half8 hv;
#pragma unroll
    for (int j = 0; j < 8; ++j) hv[j] = (_Float16)src[(size_t)j * HWS];
    *(half8*)&x16[(size_t)id * 8] = hv;
}

// ---------------------------------------------------------------------------
// h0 = sum_t x; c0 = h0.  c stays f32 [B][C][HW]; h emitted f16 blocked.
// ---------------------------------------------------------------------------
__global__ void init_hc(const float* __restrict__ x, _Float16* __restrict__ h16,
                        float* __restrict__ c) {
    int id = blockIdx.x * 256 + threadIdx.x;
    if (id >= BB * NCG * HWS) return;
    int p = id % HWS;
    int cig = (id / HWS) % NCG;
    int b = id / (HWS * NCG);
    float s[8];
#pragma unroll
    for (int j = 0; j < 8; ++j) s[j] = 0.f;
#pragma unroll
    for (int t = 0; t < TT; ++t) {
        const float* src = x + (((size_t)b * TT + t) * CC + cig * 8) * HWS + p;
#pragma unroll
        for (int j = 0; j < 8; ++j) s[j] += src[(size_t)j * HWS];
    }
    half8 hv;
    float* cp = c + ((size_t)b * CC + cig * 8) * HWS + p;
#pragma unroll
    for (int j = 0; j < 8; ++j) { cp[(size_t)j * HWS] = s[j]; hv[j] = (_Float16)s[j]; }
    *(half8*)&h16[(size_t)id * 8] = hv;
}

// ---------------------------------------------------------------------------
// xtilde16[b][cig][p][8] = (f16)(x_f32[b,t,ci,p] * a[b,p])
// ---------------------------------------------------------------------------
__global__ void xtilde_kernel(const float* __restrict__ xt, const float* __restrict__ a,
                              _Float16* __restrict__ xt16) {
    int id = blockIdx.x * 256 + threadIdx.x;
    if (id >= BB * NCG * HWS) return;
    int p = id % HWS;
    int cig = (id / HWS) % NCG;
    int b = id / (HWS * NCG);
    float sc = a[(size_t)b * HWS + p];
    const float* src = xt + ((size_t)b * TT * CC + cig * 8) * HWS + p;
    half8 hv;
#pragma unroll
    for (int j = 0; j < 8; ++j) hv[j] = (_Float16)(src[(size_t)j * HWS] * sc);
    *(half8*)&xt16[(size_t)id * 8] = hv;
}

// ---------------------------------------------------------------------------
// Pack weights to f16: layout [kg=k/8][Cout][k%8]
// ---------------------------------------------------------------------------
__global__ void pack_weights(const float* __restrict__ W1,
                             const float* __restrict__ W2,
                             _Float16* __restrict__ wt, int Cout) {
    int idx = blockIdx.x * 256 + threadIdx.x;
    if (idx >= 4608 * Cout) return;
    int k = idx / Cout;
    int n = idx - k * Cout;
    float v = (k < 2304) ? W1[(size_t)k * Cout + n]
                         : W2[(size_t)(k - 2304) * Cout + n];
    wt[((size_t)(k >> 3) * Cout + n) * 8 + (k & 7)] = (_Float16)v;
}

// ---------------------------------------------------------------------------
// MFMA dual 3x3 conv, f16 blocked activations [cig][1200][8].
// CHAIN-BREAKING WEIGHT PREFETCH: R0-R9's invariant ~51us = ~9 serialized
// L2 round-trips per kiter (weights consumed 0-4 taps after issue; per-tap
// wall ~300-600cy < loaded-L2 latency ~1000cy). Fix: 5-slot rolling prefetch
// at global-tap granularity g=k*9+t — step g consumes slot S[g%5] then
// reloads it for step g+5 (>=5-tap = ~3200cy distance; boundary-crossing
// loads arrive before the barrier's vmcnt drain). stage_issue moved POST-
// barrier. All slot/tap indices become compile-time constants after the
// mandatory full unroll of the 9-step tap loop (const not constexpr: the
// C++ front end sees runtime t; LLVM folds it post-unroll — rule #20 holds,
// verified via VGPR count / absence of scratch). Plain __syncthreads.
// ---------------------------------------------------------------------------
template<int NW, int NZ, int NY, int ZT>
__global__ __launch_bounds__(256, 2) void conv_mfma(
    const _Float16* __restrict__ in0, long bs0,
    const _Float16* __restrict__ in1, long bs1,
    const _Float16* __restrict__ wt,
    const float* __restrict__ b1, const float* __restrict__ b2,
    float* __restrict__ out, int Cout)
{
    constexpr int NK = 8 / NZ;                      // K-iters (32 ci each)
    constexpr int SLICES = NY * ZT;
    constexpr int PERX = SLICES / 8;                // slices per XCD
    constexpr int MU = 60;                          // M-units per slice
    __shared__ alignas(16) _Float16 s_a[2][4 * PL * 8];

    const int tid = threadIdx.x;
    const int l = tid & 63, wv = tid >> 6;
    const int q = l >> 4, r = l & 15;

    // ---- XCD-homed slice decode ----
    const int lin = blockIdx.x;
    const int xcd = lin & 7;
    const int idx = lin >> 3;
    const int sl = xcd * PERX + idx / MU;
    const int mb = idx % MU;
    const int zz = sl / NY;
    const int yy = sl - zz * NY;

    const int b = mb / 15;
    const int pix0 = (mb % 15) * 80;
    const int y0 = (mb % 15) * 2;
    const int n0 = yy * (4 * NW * 16) + wv * (NW * 16);
    const int src = zz / NZ;
    const int ci_start = (zz % NZ) * (CC / NZ);
    const int kgb0 = src * 288 + (ci_start >> 3);

    const _Float16* inp = src ? (in1 + (size_t)b * bs1) : (in0 + (size_t)b * bs0);

    // ---- per-thread staging geometry (3 items) ----
    bool iv[3], pv[3];
    const _Float16* pj[3];
    int ldsoff[3];
#pragma unroll
    for (int j = 0; j < 3; ++j) {
        int item = tid + j * 256;
        iv[j] = item < 672;
        int it = iv[j] ? item : 0;
        int cig = it / 168;
        int pix = it - cig * 168;
        int row = pix / 42;
        int px = pix - row * 42;
        int xx = px - 1, yy2 = y0 + row - 1;
        pv[j] = iv[j] && xx >= 0 && xx < WW && yy2 >= 0 && yy2 < HH;
        pj[j] = inp + ((size_t)((ci_start >> 3) + cig) * HWS + yy2 * WW + xx) * 8;
        ldsoff[j] = (cig * PL + pix) * 8;
    }

    // ---- accumulators ----
    f32x4 acc[5][NW];
#pragma unroll
    for (int nt = 0; nt < NW; ++nt) {
        int co = n0 + nt * 16 + r;
        float bias = (zz == 0) ? (b1[co] + b2[co]) : 0.f;
        f32x4 bv = {bias, bias, bias, bias};
#pragma unroll
        for (int mt = 0; mt < 5; ++mt) acc[mt][nt] = bv;
    }

    // ---- per-mt LDS pixel base ----
    int hbase[5];
#pragma unroll
    for (int m5 = 0; m5 < 5; ++m5) {
        int p = m5 * 16 + r;
        int ry = p / 40;
        int rx = p - ry * 40;
        hbase[m5] = ry * 42 + rx;
    }

    // ---- staging: pure b128 copy; issue post-barrier, write at kiter end ----
    half8 sr[3];
    auto stage_issue = [&](int kk) {
#pragma unroll
        for (int j = 0; j < 3; ++j) if (pv[j])
            sr[j] = *(const half8*)(pj[j] + (size_t)kk * (4 * HWS * 8));
    };
    auto stage_write = [&](int kk) {
#pragma unroll
        for (int j = 0; j < 3; ++j) if (iv[j]) {
            half8 hv = {0, 0, 0, 0, 0, 0, 0, 0};
            if (pv[j]) hv = sr[j];
            *(half8*)&s_a[kk & 1][ldsoff[j]] = hv;
        }
    };

    const half8* wp = (const half8*)wt;
    half8 S[5][NW];                                  // 5-slot rolling prefetch

#define WLOAD(SLOT, KK, TAP) do {                                          \
    const int kg_ = kgb0 + (KK) * 4 + (TAP) * 32 + q;                      \
    _Pragma("unroll")                                                      \
    for (int nt = 0; nt < NW; ++nt)                                        \
        S[SLOT][nt] = wp[(size_t)kg_ * Cout + n0 + nt * 16 + r];           \
} while (0)

#define CTAP(SLOT, TAP) do {                                               \
    const int dy_ = (TAP) / 3, dx_ = (TAP) % 3;                            \
    _Pragma("unroll")                                                      \
    for (int mt = 0; mt < 5; ++mt) {                                       \
        half8 af = *(const half8*)&s_a[k & 1]                              \
            [(q * PL + hbase[mt] + dy_ * 42 + dx_) * 8];                   \
        _Pragma("unroll")                                                  \
        for (int nt = 0; nt < NW; ++nt)                                    \
            acc[mt][nt] = __builtin_amdgcn_mfma_f32_16x16x32_f16(          \
                af, S[SLOT][nt], acc[mt][nt], 0, 0, 0);                    \
    }                                                                      \
} while (0)

    // prologue: stage tile 0; prime slots with kiter-0 taps 0-4
    stage_issue(0);
    stage_write(0);
#pragma unroll
    for (int s = 0; s < 5; ++s) WLOAD(s, 0, s);

#pragma unroll
    for (int k = 0; k < NK; ++k) {
        __syncthreads();                    // drains loads issued >=5 taps ago
        __builtin_amdgcn_s_setprio(1);
        if (k + 1 < NK) stage_issue(k + 1); // post-barrier: 8-tap budget
#pragma unroll
        for (int t = 0; t < 9; ++t) {
            const int g = k * 9 + t;        // global tap step (folded at unroll)
            CTAP(g % 5, t);                 // consume slot
            const int gn = g + 5;           // refill same slot, 5 steps ahead
            if (gn < NK * 9) WLOAD(g % 5, gn / 9, gn % 9);
        }
        __builtin_amdgcn_s_setprio(0);
        __builtin_amdgcn_sched_barrier(0);  // pin loads inside the kiter body
        if (k + 1 < NK) stage_write(k + 1); // other buffer -> no extra barrier
    }
#undef WLOAD
#undef CTAP

    out += (size_t)zz * BB * Cout * HWS;
#pragma unroll
    for (int mt = 0; mt < 5; ++mt) {
#pragma unroll
        for (int nt = 0; nt < NW; ++nt) {
            int co = n0 + nt * 16 + r;
            int p = pix0 + mt * 16 + q * 4;
            *(f32x4*)&out[((size_t)b * Cout + co) * HWS + p] = acc[mt][nt];
        }
    }
}

// ---------------------------------------------------------------------------
// att = tanh(a0 + a1 + a2 + a3)  (4 stacked K-split partials, float4 loads)
// ---------------------------------------------------------------------------
__global__ void add_tanh4(const float* __restrict__ a0,
                          float* __restrict__ o, int n4) {
    int id = blockIdx.x * 256 + threadIdx.x;
    if (id >= n4) return;
    const f32x4* av = (const f32x4*)a0;
    f32x4 s = av[id] + av[id + (size_t)n4] + av[id + 2 * (size_t)n4]
            + av[id + 3 * (size_t)n4];
    f32x4 rr;
#pragma unroll
    for (int j = 0; j < 4; ++j) rr[j] = tanhf(s[j]);
    ((f32x4*)o)[id] = rr;
}

// ---------------------------------------------------------------------------
// K-split attention score
// ---------------------------------------------------------------------------
__global__ __launch_bounds__(256) void att_e_part(
    const float* __restrict__ att, const float* __restrict__ Va,
    float* __restrict__ part)
{
    __shared__ float red[4][64];
    const int lane = threadIdx.x & 63, wv = threadIdx.x >> 6;
    const int p = blockIdx.x * 64 + lane;
    const int b = blockIdx.y, ch = blockIdx.z;
    const bool valid = (p < HWS);
    const int pc = valid ? p : 0;
    const int y = pc / WW, x = pc - (pc / WW) * WW;

    float acc = 0.f;
    if (valid) {
        const int ca0 = ch * 32 + wv * 8;
#pragma unroll
        for (int j = 0; j < 8; ++j) {
            const int ca = ca0 + j;
            const float* base = att + ((size_t)b * CC + ca) * HWS;
            const float* va = Va + ca;
#pragma unroll
            for (int dy = 0; dy < 3; ++dy) {
                int yy = y + dy - 1;
                if (yy < 0 || yy >= HH) continue;
#pragma unroll
                for (int dx = 0; dx < 3; ++dx) {
                    int xx = x + dx - 1;
                    if (xx < 0 || xx >= WW) continue;
                    acc = fmaf(base[yy * WW + xx], va[(dy * 3 + dx) * CC], acc);
                }
            }
        }
    }
    red[wv][lane] = acc;
    __syncthreads();
    if (wv == 0 && valid)
        part[((size_t)b * 8 + ch) * HWS + p] =
            red[0][lane] + red[1][lane] + red[2][lane] + red[3][lane];
}

// ---------------------------------------------------------------------------
// softmax over HW per batch, summing the 8 K-split partials first (in LDS)
// ---------------------------------------------------------------------------
__global__ __launch_bounds__(256) void softmax_kernel(
    const float* __restrict__ part, float* __restrict__ a)
{
    __shared__ float se[HWS];
    __shared__ float red[256];
    int b = blockIdx.x;
    int tid = threadIdx.x;

    for (int i = tid; i < HWS; i += 256) {
        float s = 0.f;
#pragma unroll
        for (int ch = 0; ch < 8; ++ch)
            s += part[((size_t)b * 8 + ch) * HWS + i];
        se[i] = s;
    }
    __syncthreads();

    float m = -1e30f;
    for (int i = tid; i < HWS; i += 256) m = fmaxf(m, se[i]);
    red[tid] = m;
    __syncthreads();
    for (int s = 128; s > 0; s >>= 1) {
        if (tid < s) red[tid] = fmaxf(red[tid], red[tid + s]);
        __syncthreads();
    }
    m = red[0];
    __syncthreads();

    float sum = 0.f;
    for (int i = tid; i < HWS; i += 256) {
        float v = expf(se[i] - m);
        se[i] = v;
        sum += v;
    }
    red[tid] = sum;
    __syncthreads();
    for (int s = 128; s > 0; s >>= 1) {
        if (tid < s) red[tid] += red[tid + s];
        __syncthreads();
    }
    float inv = 1.f / red[0];
    for (int i = tid; i < HWS; i += 256)
        a[(size_t)b * HWS + i] = se[i] * inv;
}

// ---------------------------------------------------------------------------
// LSTM gate update; emits h16 (blocked f16) always, h f32 only on last step.
// ---------------------------------------------------------------------------
__global__ void gate_update(const float* __restrict__ g0, const float* __restrict__ g1,
                            float* __restrict__ c, _Float16* __restrict__ h16,
                            float* __restrict__ h32) {
    int id = blockIdx.x * 256 + threadIdx.x;
    if (id >= BB * NCG * HWS) return;
    int p = id % HWS;
    int cig = (id / HWS) % NCG;
    int b = id / (HWS * NCG);
    const int ci0 = cig * 8;
    half8 hv;
#pragma unroll
    for (int j = 0; j < 8; ++j) {
        size_t base = ((size_t)b * 4 * CC + ci0 + j) * HWS + p;
        float gi = g0[base] + g1[base];
        float gf = g0[base + (size_t)CHW] + g1[base + (size_t)CHW];
        float gc = g0[base + 2 * (size_t)CHW] + g1[base + 2 * (size_t)CHW];
        float go = g0[base + 3 * (size_t)CHW] + g1[base + 3 * (size_t)CHW];
        float i_ = 1.f / (1.f + expf(-gi));
        float f_ = 1.f / (1.f + expf(-gf));
        float o_ = 1.f / (1.f + expf(-go));
        size_t cix = ((size_t)b * CC + ci0 + j) * HWS + p;
        float cn = f_ * c[cix] + i_ * tanhf(gc);
        c[cix] = cn;
        float hn = o_ * tanhf(cn);
        hv[j] = (_Float16)hn;
        if (h32) h32[cix] = hn;
    }
    *(half8*)&h16[(size_t)id * 8] = hv;
}

// ---------------------------------------------------------------------------
extern "C" void kernel_launch(void* const* d_in, const int* in_sizes, int n_in,
                              void* d_out, int out_size, void* d_ws, size_t ws_size,
                              hipStream_t stream) {
    const float* x   = (const float*)d_in[0];
    const float* Wa  = (const float*)d_in[1];
    const float* ba  = (const float*)d_in[2];
    const float* Ua  = (const float*)d_in[3];
    const float* bua = (const float*)d_in[4];
    const float* Va  = (const float*)d_in[5];
    const float* Wx  = (const float*)d_in[6];
    const float* bx  = (const float*)d_in[7];
    const float* Uh  = (const float*)d_in[8];
    const float* bh  = (const float*)d_in[9];
    float* out = (float*)d_out;

    char* wsb = (char*)d_ws;
    const size_t NCHW = (size_t)BB * CHW;
    _Float16* wtg  = (_Float16*)wsb;              wsb += (size_t)4608 * 1024 * 2;
    _Float16* wta  = (_Float16*)wsb;              wsb += (size_t)4608 * 256 * 2;
    _Float16* x16  = (_Float16*)wsb;              wsb += (size_t)BB * TT * PXS * 2;
    _Float16* h16  = (_Float16*)wsb;              wsb += (size_t)BB * PXS * 2;
    _Float16* xt16 = (_Float16*)wsb;              wsb += (size_t)BB * PXS * 2;
    float* cb   = (float*)wsb;                    wsb += NCHW * 4;
    float* g01  = (float*)wsb;                    wsb += 8 * NCHW * 4;   // z-stacked
    float* att  = (float*)wsb;                    wsb += NCHW * 4;
    float* part = (float*)wsb;                    wsb += (size_t)BB * 8 * HWS * 4;
    float* a    = (float*)wsb;
    // att01 (4 z-stacked partials, Cout=256) aliases g01 (disjoint lifetime)
    float* att01 = g01;

    pack_weights<<<dim3((4608 * 1024 + 255) / 256), dim3(256), 0, stream>>>(
        Wx, Uh, wtg, 1024);
    pack_weights<<<dim3((4608 * 256 + 255) / 256), dim3(256), 0, stream>>>(
        Wa, Ua, wta, 256);
    pack_x16<<<dim3((BB * TT * NCG * HWS + 255) / 256), dim3(256), 0, stream>>>(
        x, x16);

    const int nblk = BB * NCG * HWS;              // 153600
    init_hc<<<dim3((nblk + 255) / 256), dim3(256), 0, stream>>>(x, h16, cb);

    const int n4 = (int)(NCHW / 4);

    for (int t = 0; t < TT; ++t) {
        // attention partials: NW=2, 8 slices x 60 M-units = 480 blocks, NK=4.
        conv_mfma<2, 2, 2, 4><<<dim3(480), dim3(256), 0, stream>>>(
            h16, (long)PXS, x16 + (size_t)t * PXS, (long)TT * PXS,
            wta, ba, bua, att01, 256);
        add_tanh4<<<dim3((n4 + 255) / 256), dim3(256), 0, stream>>>(
            att01, att, n4);

        att_e_part<<<dim3(19, BB, 8), dim3(256), 0, stream>>>(att, Va, part);
        softmax_kernel<<<dim3(BB), dim3(256), 0, stream>>>(part, a);

        xtilde_kernel<<<dim3((nblk + 255) / 256), dim3(256), 0, stream>>>(
            x + (size_t)t * CHW, a, xt16);

        // gates: NW=4, 8 slices x 60 M-units = 480 blocks, NK=8.
        conv_mfma<4, 1, 4, 2><<<dim3(480), dim3(256), 0, stream>>>(
            xt16, (long)PXS, h16, (long)PXS, wtg, bx, bh, g01, 1024);

        gate_update<<<dim3((nblk + 255) / 256), dim3(256), 0, stream>>>(
            g01, g01 + 4 * NCHW, cb, h16, (t == TT - 1) ? out : nullptr);
    }
}